// Round 11
// baseline (415.011 us; speedup 1.0000x reference)
//
#include <hip/hip_runtime.h>
#include <hip/hip_bf16.h>
#include <math.h>

#define NNODES 50000
#define NEDGES 800000
#define HNB 64                  // histogram chunks
#define HCHUNK (NEDGES / HNB)   // 12500 edges per chunk
#define HBINS 50176             // 196*256, >= NNODES, %4==0
#define SCAN_NB 196             // HBINS/256

typedef short s8v __attribute__((ext_vector_type(8)));
typedef float f4v __attribute__((ext_vector_type(4)));
typedef unsigned char uchar8;
using bf16 = __hip_bfloat16;

static __device__ __forceinline__ float bflo(unsigned int x) {
    union { unsigned int i; float f; } c; c.i = x << 16; return c.f;
}
static __device__ __forceinline__ float bfhi(unsigned int x) {
    union { unsigned int i; float f; } c; c.i = x & 0xffff0000u; return c.f;
}

static __device__ __forceinline__ void gload16(const void* g, void* l) {
    __builtin_amdgcn_global_load_lds(
        (const __attribute__((address_space(1))) unsigned int*)g,
        (__attribute__((address_space(3))) unsigned int*)l, 16, 0, 0);
}

// ---------------- fused weight pack (3 matrices) ----------------
// BT[n][k] = (n < C) ? W[k][n] : LW[k][n-C]  (K-contiguous rows so a GEMM
// block's 128-col B-slice is one contiguous 64KB run)

#define M1 (256 * 512)
#define M2 (256 * 512)
#define M3 (256 * 256)

__global__ __launch_bounds__(256) void k_packall(
        const float* __restrict__ w1, const float* __restrict__ lw1,
        const float* __restrict__ w2, const float* __restrict__ lw2,
        const float* __restrict__ w3, const float* __restrict__ lw3,
        bf16* __restrict__ o1, bf16* __restrict__ o2, bf16* __restrict__ o3) {
    int i = blockIdx.x * 256 + threadIdx.x;
    const float* W; const float* LW; bf16* O; int C; int j;
    if (i < M1)            { W = w1; LW = lw1; O = o1; C = 256; j = i; }
    else if (i < M1 + M2)  { W = w2; LW = lw2; O = o2; C = 256; j = i - M1; }
    else                   { W = w3; LW = lw3; O = o3; C = 128; j = i - M1 - M2; }
    int n = j >> 8, k = j & 255;   // K = 256 for all
    float v = (n < C) ? W[k * C + n] : LW[k * C + (n - C)];
    O[j] = __float2bfloat16(v);
}

// ---------------- degree histograms via LDS, u8 bins ----------------
// row 0: out-degree counts (for rsqrt norm). row 1: in-degree counts AND the
// within-(chunk,node) rank of every dst-edge (the LDS atomicAdd return value,
// free) -> atomic-free scatter.

__global__ __launch_bounds__(256) void k_hist(const int* __restrict__ ei,
                                              uchar8* __restrict__ partials,
                                              uchar8* __restrict__ lrank) {
    __shared__ unsigned int h32[HBINS / 4];   // 50176 B LDS (4x8-bit packed)
    int b = blockIdx.x, row = blockIdx.y, t = threadIdx.x;
    for (int i = t; i < HBINS / 4; i += 256) h32[i] = 0;
    __syncthreads();
    int beg = b * HCHUNK, end = beg + HCHUNK;
    const int* p = ei + (size_t)row * NEDGES;
    if (row == 0) {
        for (int e = beg + t; e < end; e += 256) {
            int id = p[e];
            atomicAdd(&h32[id >> 2], 1u << (8 * (id & 3)));
        }
    } else {
        for (int e = beg + t; e < end; e += 256) {
            int id = p[e];
            unsigned int old = atomicAdd(&h32[id >> 2], 1u << (8 * (id & 3)));
            lrank[e] = (uchar8)((old >> (8 * (id & 3))) & 0xffu);
        }
    }
    __syncthreads();
    unsigned int* o32 = (unsigned int*)(partials + ((size_t)row * HNB + b) * HBINS);
    for (int i = t; i < HBINS / 4; i += 256) o32[i] = h32[i];
}

// row 0: sum partials -> rsqrt table.
// row 1: in-place exclusive scan of partials over chunks, total in_cnt, and
//        per-256-node block sums for the scan.
__global__ __launch_bounds__(256) void k_hist_reduce(uchar8* __restrict__ partials,
                                                     float* __restrict__ rsqrt_out,
                                                     int* __restrict__ in_cnt,
                                                     int* __restrict__ block_sums) {
    __shared__ int sm[256];
    int row = blockIdx.y;
    int i = blockIdx.x * 256 + threadIdx.x;
    if (row == 0) {
        const uchar8* p = partials + i;
        int s = 0;
#pragma unroll 4
        for (int b = 0; b < HNB; ++b) s += p[(size_t)b * HBINS];
        if (i < NNODES) rsqrt_out[i] = rsqrtf((float)s);
    } else {
        uchar8* p = partials + (size_t)HNB * HBINS + i;
        int run = 0;
        for (int b = 0; b < HNB; ++b) {
            int c = p[(size_t)b * HBINS];
            p[(size_t)b * HBINS] = (uchar8)run;
            run += c;
        }
        if (i < NNODES) in_cnt[i] = run;
        sm[threadIdx.x] = (i < NNODES) ? run : 0;
        __syncthreads();
        for (int off = 128; off > 0; off >>= 1) {
            if (threadIdx.x < off) sm[threadIdx.x] += sm[threadIdx.x + off];
            __syncthreads();
        }
        if (threadIdx.x == 0) block_sums[blockIdx.x] = sm[0];
    }
}

// ---------------- scan (merged: per-block base recomputed locally) ----------------

__global__ void k_scan_final(const int* __restrict__ in_cnt, const int* __restrict__ block_sums,
                             int* __restrict__ offsets) {
    __shared__ int s[256];
    __shared__ int sb[256];
    int b = blockIdx.x, t = threadIdx.x;
    // base = sum of block_sums[0..b-1] (196 ints, L2-hot, redundant per block)
    sb[t] = (t < b) ? block_sums[t] : 0;
    __syncthreads();
    for (int off = 128; off > 0; off >>= 1) {
        if (t < off) sb[t] += sb[t + off];
        __syncthreads();
    }
    int base = sb[0];

    int i = b * 256 + t;
    int v = (i < NNODES) ? in_cnt[i] : 0;
    s[t] = v;
    __syncthreads();
    for (int off = 1; off < 256; off <<= 1) {
        int u = (t >= off) ? s[t - off] : 0;
        __syncthreads();
        s[t] += u;
        __syncthreads();
    }
    int excl = s[t] - v + base;
    if (i < NNODES) offsets[i] = excl;
    if (i == NNODES - 1) offsets[NNODES] = excl + v;
}

// atomic-free counting-sort scatter:
// pos = offsets[dst] + base[chunk(e)][dst] + lrank[e]  (bijective by construction)
__global__ __launch_bounds__(256) void k_scatter_free(const int* __restrict__ ei,
                                                      const int* __restrict__ offsets,
                                                      const uchar8* __restrict__ partials,
                                                      const uchar8* __restrict__ lrank,
                                                      int* __restrict__ src_sorted) {
    int e = blockIdx.x * 256 + threadIdx.x;
    if (e < NEDGES) {
        int r = ei[e], c = ei[NEDGES + e];
        int b = e / HCHUNK;
        int pos = offsets[c] + (int)partials[(size_t)(HNB + b) * HBINS + c] + (int)lrank[e];
        src_sorted[pos] = r;
    }
}

// ---------------- fused aggregate + residual + bias + activation ----------------
// One 64-thread block per node (best-measured form, U=4, unchanged from R10).
template<int D, int ACT>
__global__ __launch_bounds__(64) void k_agg_fused(const bf16* __restrict__ xw,
                                                  const bf16* __restrict__ xlw,
                                                  const int* __restrict__ offsets,
                                                  const int* __restrict__ src_sorted,
                                                  const float* __restrict__ rsqrt_out,
                                                  const float* __restrict__ bias,
                                                  void* __restrict__ out) {
    const int L = D / 8;    // 32 (D=256) or 16 (D=128)
    const int G = 64 / L;   // 2 or 4
    const int U = 4;
    int lane = threadIdx.x;
    int v = blockIdx.x;
    int g = lane / L, sl = lane % L;

    int beg = offsets[v], end = offsets[v + 1];
    int deg = end - beg;
    int dcap = min(deg, 64);

    int id = 0; float wl = 0.f;
    if (lane < dcap) {
        id = src_sorted[beg + lane];
        wl = rsqrt_out[id];
    }

    float acc[U][8];
#pragma unroll
    for (int u = 0; u < U; ++u)
#pragma unroll
        for (int c = 0; c < 8; ++c) acc[u][c] = 0.f;

    const ushort* base = (const ushort*)xw + sl * 8;

    for (int e0 = 0; e0 < dcap; e0 += G * U) {
#pragma unroll
        for (int u = 0; u < U; ++u) {
            int e = e0 + u * G + g;
            int s = __shfl(id, e & 63, 64);
            float w = __shfl(wl, e & 63, 64);
            if (e >= dcap) w = 0.f;
            uint4 q = *(const uint4*)(base + (size_t)s * D);
            acc[u][0] += w * bflo(q.x); acc[u][1] += w * bfhi(q.x);
            acc[u][2] += w * bflo(q.y); acc[u][3] += w * bfhi(q.y);
            acc[u][4] += w * bflo(q.z); acc[u][5] += w * bfhi(q.z);
            acc[u][6] += w * bflo(q.w); acc[u][7] += w * bfhi(q.w);
        }
    }
    for (int j = beg + 64 + g; j < end; j += G) {
        int s = src_sorted[j];
        float w = rsqrt_out[s];
        uint4 q = *(const uint4*)(base + (size_t)s * D);
        acc[0][0] += w * bflo(q.x); acc[0][1] += w * bfhi(q.x);
        acc[0][2] += w * bflo(q.y); acc[0][3] += w * bfhi(q.y);
        acc[0][4] += w * bflo(q.z); acc[0][5] += w * bfhi(q.z);
        acc[0][6] += w * bflo(q.w); acc[0][7] += w * bfhi(q.w);
    }

#pragma unroll
    for (int c = 0; c < 8; ++c) acc[0][c] = (acc[0][c] + acc[1][c]) + (acc[2][c] + acc[3][c]);
#pragma unroll
    for (int d = 32; d >= L; d >>= 1) {
#pragma unroll
        for (int c = 0; c < 8; ++c) acc[0][c] += __shfl_down(acc[0][c], d, 64);
    }

    if (lane < L) {
        float sc = (deg > 0) ? rsqrtf((float)deg) : 0.f;
        const ushort* lwp = (const ushort*)xlw + (size_t)v * D + sl * 8;
        uint4 ql = *(const uint4*)lwp;
        const float* bp = bias + sl * 8;
        float4 b0 = *(const float4*)bp, b1 = *(const float4*)(bp + 4);
        float h[8];
        h[0] = acc[0][0] * sc + bflo(ql.x) + b0.x;
        h[1] = acc[0][1] * sc + bfhi(ql.x) + b0.y;
        h[2] = acc[0][2] * sc + bflo(ql.y) + b0.z;
        h[3] = acc[0][3] * sc + bfhi(ql.y) + b0.w;
        h[4] = acc[0][4] * sc + bflo(ql.z) + b1.x;
        h[5] = acc[0][5] * sc + bfhi(ql.z) + b1.y;
        h[6] = acc[0][6] * sc + bflo(ql.w) + b1.z;
        h[7] = acc[0][7] * sc + bfhi(ql.w) + b1.w;
        if (ACT == 1) {
            union { bf16 hh[8]; uint4 u; } o;
#pragma unroll
            for (int c = 0; c < 8; ++c) o.hh[c] = __float2bfloat16(fmaxf(h[c], 0.f));
            *(uint4*)((ushort*)out + (size_t)v * D + sl * 8) = o.u;
        } else {
            float r[8];
#pragma unroll
            for (int c = 0; c < 8; ++c) r[c] = 1.f / (1.f + expf(-h[c]));
            float* op = (float*)out + (size_t)v * D + sl * 8;
            *(float4*)op = (float4){r[0], r[1], r[2], r[3]};
            *(float4*)(op + 4) = (float4){r[4], r[5], r[6], r[7]};
        }
    }
}

// ---------------- B-resident MFMA GEMM: A[N,256] @ BT[C2,256]^T -> xw | xlw ----------------
// Each block owns ONE 128-col B-slice: loaded into LDS ONCE (64KB, linear
// gload16 burst, 3-bit XOR swizzle on within-row chunks), then the block
// grid-strides over ~3 row-tiles staging only A per K-step (2 gload16, dbuf).
// Removes the 100MB of per-block B re-staging (R6-R9's common defect) and the
// 8-way As bank conflict (64B rows -> 2 bank-quads; fixed by sigma=(row&3) XOR,
// both-sides per the gload16 linear-dest rule: source chunk pre-permuted).
// Epilogue routes 128-wide n-tiles to xw (cols < C2/2) or xlw.
template<int C2, bool A_BF16>
__global__ __launch_bounds__(256) void k_gemm5(const void* __restrict__ Aptr,
                                               const bf16* __restrict__ BT,
                                               bf16* __restrict__ XW,
                                               bf16* __restrict__ XLW) {
    constexpr int R = NNODES;
    constexpr int DH = C2 / 2;                 // 256 or 128
    constexpr int GY = C2 / 128;               // 4 or 2
    constexpr int NRT = 391;                   // row-tiles
    constexpr int NB = (GY == 4) ? 131 : 196;  // row-strips per column
    __shared__ bf16 Bs[128 * 256];             // 64 KB, K-resident
    __shared__ bf16 As[2][128 * 32];           // 16 KB dbuf

    int bid = blockIdx.x;
    int ct = bid % GY;
    int strip = bid / GY;
    int n0 = ct * 128;

    int t = threadIdx.x;
    int wave = t >> 6, lane = t & 63;
    int wr = wave >> 1, wc = wave & 1;
    int lr = lane & 15;
    int kch = lane >> 4;                       // k-chunk 0..3 within a BK=32 row

    char* AsB0 = (char*)As[0];
    char* AsB1 = (char*)As[1];
    char* BsB  = (char*)Bs;

    // ---- load B slice once: LDS[c] = global[c ^ ((c>>5)&7)]  (row = c>>5) ----
    const bf16* Bsrc = BT + (size_t)n0 * 256;
#pragma unroll
    for (int i = 0; i < 16; ++i) {
        int c  = i * 256 + t;
        int cs = c ^ ((c >> 5) & 7);
        gload16(Bsrc + (size_t)cs * 8, BsB + i * 4096 + wave * 1024);
    }

    // A staging coords: thread t -> LDS rows sr, sr+64; source chunk swizzled
    int sr  = t >> 2;
    int sks = (((t & 3) ^ (sr & 3))) * 8;      // sigma2 within-row k offset (elems)
    int fr  = t >> 1, fs = (t & 1) * 16;       // fp32 path: row, k-elems offset

    const bf16*  Ab  = (const bf16*)Aptr;
    const float* Af0 = (const float*)Aptr;

    bool first = true;
    for (int rt = strip; rt < NRT; rt += NB) {
        int r0 = rt * 128;

        f4v acc[4][4];
#pragma unroll
        for (int mi = 0; mi < 4; ++mi)
#pragma unroll
            for (int ni = 0; ni < 4; ++ni) acc[mi][ni] = (f4v){0.f, 0.f, 0.f, 0.f};

        float4 f0, f1, f2, f3;

        // ---- prologue: stage K-tile 0 into As[0] ----
        if (A_BF16) {
            gload16(Ab + (size_t)min(r0 + sr, R - 1) * 256 + sks, AsB0 + wave * 1024);
            gload16(Ab + (size_t)min(r0 + sr + 64, R - 1) * 256 + sks, AsB0 + 4096 + wave * 1024);
        } else {
            const float* Af = Af0 + (size_t)min(r0 + fr, R - 1) * 256 + fs;
            f0 = ((const float4*)Af)[0]; f1 = ((const float4*)Af)[1];
            f2 = ((const float4*)Af)[2]; f3 = ((const float4*)Af)[3];
            union { bf16 h[16]; uint4 u[2]; } cv;
            cv.h[0]  = __float2bfloat16(f0.x); cv.h[1]  = __float2bfloat16(f0.y);
            cv.h[2]  = __float2bfloat16(f0.z); cv.h[3]  = __float2bfloat16(f0.w);
            cv.h[4]  = __float2bfloat16(f1.x); cv.h[5]  = __float2bfloat16(f1.y);
            cv.h[6]  = __float2bfloat16(f1.z); cv.h[7]  = __float2bfloat16(f1.w);
            cv.h[8]  = __float2bfloat16(f2.x); cv.h[9]  = __float2bfloat16(f2.y);
            cv.h[10] = __float2bfloat16(f2.z); cv.h[11] = __float2bfloat16(f2.w);
            cv.h[12] = __float2bfloat16(f3.x); cv.h[13] = __float2bfloat16(f3.y);
            cv.h[14] = __float2bfloat16(f3.z); cv.h[15] = __float2bfloat16(f3.w);
            int cb = (t & 1) * 2;
            *(uint4*)(AsB0 + fr * 64 + (((cb + 0) ^ (fr & 3)) << 4)) = cv.u[0];
            *(uint4*)(AsB0 + fr * 64 + (((cb + 1) ^ (fr & 3)) << 4)) = cv.u[1];
        }
        __syncthreads();   // drains B burst (first iter) + A prologue
        first = false;

        for (int kt = 0; kt < 8; ++kt) {
            char* cur = (kt & 1) ? AsB1 : AsB0;
            char* nxt = (kt & 1) ? AsB0 : AsB1;
            int k1 = (kt + 1) * 32;
            bool more = (kt < 7);

            // issue next A-tile loads first (hide under MFMAs below)
            if (more) {
                if (A_BF16) {
                    gload16(Ab + (size_t)min(r0 + sr, R - 1) * 256 + k1 + sks, nxt + wave * 1024);
                    gload16(Ab + (size_t)min(r0 + sr + 64, R - 1) * 256 + k1 + sks, nxt + 4096 + wave * 1024);
                } else {
                    const float* Af = Af0 + (size_t)min(r0 + fr, R - 1) * 256 + k1 + fs;
                    f0 = ((const float4*)Af)[0]; f1 = ((const float4*)Af)[1];
                    f2 = ((const float4*)Af)[2]; f3 = ((const float4*)Af)[3];
                }
            }

            // compute current tile: A from As[cur] (sigma2), B from resident Bs (sigma3)
            s8v a[4], b[4];
#pragma unroll
            for (int mi = 0; mi < 4; ++mi) {
                int row = wr * 64 + mi * 16 + lr;
                a[mi] = *(const s8v*)(cur + row * 64 + ((kch ^ (row & 3)) << 4));
            }
            int ch = kt * 4 + kch;
#pragma unroll
            for (int ni = 0; ni < 4; ++ni) {
                int row = wc * 64 + ni * 16 + lr;
                b[ni] = *(const s8v*)(BsB + row * 512 + ((ch ^ (row & 7)) << 4));
            }
#pragma unroll
            for (int mi = 0; mi < 4; ++mi)
#pragma unroll
                for (int ni = 0; ni < 4; ++ni)
                    acc[mi][ni] = __builtin_amdgcn_mfma_f32_16x16x32_bf16(a[mi], b[ni], acc[mi][ni], 0, 0, 0);

            // fp32 path: convert + swizzled ds_write AFTER the MFMAs
            if (more && !A_BF16) {
                union { bf16 h[16]; uint4 u[2]; } cv;
                cv.h[0]  = __float2bfloat16(f0.x); cv.h[1]  = __float2bfloat16(f0.y);
                cv.h[2]  = __float2bfloat16(f0.z); cv.h[3]  = __float2bfloat16(f0.w);
                cv.h[4]  = __float2bfloat16(f1.x); cv.h[5]  = __float2bfloat16(f1.y);
                cv.h[6]  = __float2bfloat16(f1.z); cv.h[7]  = __float2bfloat16(f1.w);
                cv.h[8]  = __float2bfloat16(f2.x); cv.h[9]  = __float2bfloat16(f2.y);
                cv.h[10] = __float2bfloat16(f2.z); cv.h[11] = __float2bfloat16(f2.w);
                cv.h[12] = __float2bfloat16(f3.x); cv.h[13] = __float2bfloat16(f3.y);
                cv.h[14] = __float2bfloat16(f3.z); cv.h[15] = __float2bfloat16(f3.w);
                int cb = (t & 1) * 2;
                *(uint4*)(nxt + fr * 64 + (((cb + 0) ^ (fr & 3)) << 4)) = cv.u[0];
                *(uint4*)(nxt + fr * 64 + (((cb + 1) ^ (fr & 3)) << 4)) = cv.u[1];
            }
            __syncthreads();
        }

        // epilogue: route this 128-wide n-tile to xw or xlw
        bool isXW = (n0 < DH);
        bf16* OutH = isXW ? XW : XLW;
        int   c0   = isXW ? n0 : n0 - DH;

        int lq = (lane >> 4) * 4;
#pragma unroll
        for (int mi = 0; mi < 4; ++mi) {
#pragma unroll
            for (int rj = 0; rj < 4; ++rj) {
                int grow = r0 + wr * 64 + mi * 16 + lq + rj;
                if (grow < R) {
#pragma unroll
                    for (int ni = 0; ni < 4; ++ni) {
                        OutH[(size_t)grow * DH + c0 + wc * 64 + ni * 16 + lr] =
                            __float2bfloat16(acc[mi][ni][rj]);
                    }
                }
            }
        }
    }
    (void)first;
}

// ---------------- launcher ----------------

extern "C" void kernel_launch(void* const* d_in, const int* in_sizes, int n_in,
                              void* d_out, int out_size, void* d_ws, size_t ws_size,
                              hipStream_t stream) {
    const float* x   = (const float*)d_in[0];
    const int*   ei  = (const int*)d_in[1];
    const float* w1  = (const float*)d_in[3];
    const float* lw1 = (const float*)d_in[4];
    const float* lb1 = (const float*)d_in[5];
    const float* w2  = (const float*)d_in[6];
    const float* lw2 = (const float*)d_in[7];
    const float* lb2 = (const float*)d_in[8];
    const float* w3  = (const float*)d_in[9];
    const float* lw3 = (const float*)d_in[10];
    const float* lb3 = (const float*)d_in[11];
    float* out = (float*)d_out;

    char* ws = (char*)d_ws;
    size_t off = 0;
    auto alloc = [&](size_t bytes) -> void* {
        void* p = ws + off;
        off += (bytes + 255) & ~(size_t)255;
        return p;
    };
    int*    in_cnt     = (int*)alloc((size_t)HBINS * 4);
    float*  rsqrt_out  = (float*)alloc((size_t)HBINS * 4);
    int*    offsets    = (int*)alloc((size_t)(NNODES + 1) * 4);
    int*    block_sums = (int*)alloc((size_t)256 * 4);
    uchar8* partials   = (uchar8*)alloc((size_t)2 * HNB * HBINS);
    uchar8* lrank      = (uchar8*)alloc((size_t)NEDGES);
    int*    src_sorted = (int*)alloc((size_t)NEDGES * 4);
    bf16*   wcat1      = (bf16*)alloc((size_t)256 * 512 * 2);
    bf16*   wcat2      = (bf16*)alloc((size_t)256 * 512 * 2);
    bf16*   wcat3      = (bf16*)alloc((size_t)256 * 256 * 2);
    bf16*   xw         = (bf16*)alloc((size_t)NNODES * 256 * 2);   // compact gather array
    bf16*   xlw        = (bf16*)alloc((size_t)NNODES * 256 * 2);   // residual rows
    bf16*   h1         = (bf16*)alloc((size_t)NNODES * 256 * 2);
    bf16*   h2         = (bf16*)alloc((size_t)NNODES * 256 * 2);

    // fused pack (3 matrices)
    k_packall<<<(M1 + M2 + M3) / 256, 256, 0, stream>>>(
        w1, lw1, w2, lw2, w3, lw3, wcat1, wcat2, wcat3);

    // graph preprocessing: u8 LDS histograms (+rank record) -> in-place chunk
    // scan -> merged node scan -> atomic-free scatter
    k_hist<<<dim3(HNB, 2), 256, 0, stream>>>(ei, partials, lrank);
    k_hist_reduce<<<dim3(SCAN_NB, 2), 256, 0, stream>>>(partials, rsqrt_out, in_cnt, block_sums);
    k_scan_final<<<SCAN_NB, 256, 0, stream>>>(in_cnt, block_sums, offsets);
    int eblocks = (NEDGES + 255) / 256;
    k_scatter_free<<<eblocks, 256, 0, stream>>>(ei, offsets, partials, lrank, src_sorted);

    // layer 1 (A fp32)
    k_gemm5<512, false><<<4 * 131, 256, 0, stream>>>(x, wcat1, xw, xlw);
    k_agg_fused<256, 1><<<NNODES, 64, 0, stream>>>(xw, xlw, offsets, src_sorted, rsqrt_out, lb1, h1);
    // layer 2 (A bf16)
    k_gemm5<512, true><<<4 * 131, 256, 0, stream>>>(h1, wcat2, xw, xlw);
    k_agg_fused<256, 1><<<NNODES, 64, 0, stream>>>(xw, xlw, offsets, src_sorted, rsqrt_out, lb2, h2);
    // layer 3 (A bf16)
    k_gemm5<256, true><<<2 * 196, 256, 0, stream>>>(h2, wcat3, xw, xlw);
    k_agg_fused<128, 2><<<NNODES, 64, 0, stream>>>(xw, xlw, offsets, src_sorted, rsqrt_out, lb3, out);
}

// Round 12
// 394.147 us; speedup vs baseline: 1.0529x; 1.0529x over previous
//
#include <hip/hip_runtime.h>
#include <hip/hip_bf16.h>
#include <math.h>

#define NNODES 50000
#define NEDGES 800000
#define HNB 64                  // histogram chunks
#define HCHUNK (NEDGES / HNB)   // 12500 edges per chunk
#define HBINS 50176             // 196*256, >= NNODES, %4==0
#define SCAN_NB 196             // HBINS/256

typedef short s8v __attribute__((ext_vector_type(8)));
typedef float f4v __attribute__((ext_vector_type(4)));
typedef unsigned char uchar8;
using bf16 = __hip_bfloat16;

static __device__ __forceinline__ float bflo(unsigned int x) {
    union { unsigned int i; float f; } c; c.i = x << 16; return c.f;
}
static __device__ __forceinline__ float bfhi(unsigned int x) {
    union { unsigned int i; float f; } c; c.i = x & 0xffff0000u; return c.f;
}

static __device__ __forceinline__ void gload16(const void* g, void* l) {
    __builtin_amdgcn_global_load_lds(
        (const __attribute__((address_space(1))) unsigned int*)g,
        (__attribute__((address_space(3))) unsigned int*)l, 16, 0, 0);
}

#define M1 (256 * 512)
#define M2 (256 * 512)
#define M3 (256 * 256)

// ---------------- degree histograms via LDS, u8 bins ----------------
// row 0: out-degree counts (for rsqrt norm). row 1: in-degree counts AND the
// within-(chunk,node) rank of every dst-edge (the LDS atomicAdd return value,
// free) -> atomic-free scatter.

__global__ __launch_bounds__(256) void k_hist(const int* __restrict__ ei,
                                              uchar8* __restrict__ partials,
                                              uchar8* __restrict__ lrank) {
    __shared__ unsigned int h32[HBINS / 4];   // 50176 B LDS (4x8-bit packed)
    int b = blockIdx.x, row = blockIdx.y, t = threadIdx.x;
    for (int i = t; i < HBINS / 4; i += 256) h32[i] = 0;
    __syncthreads();
    int beg = b * HCHUNK, end = beg + HCHUNK;
    const int* p = ei + (size_t)row * NEDGES;
    if (row == 0) {
        for (int e = beg + t; e < end; e += 256) {
            int id = p[e];
            atomicAdd(&h32[id >> 2], 1u << (8 * (id & 3)));
        }
    } else {
        for (int e = beg + t; e < end; e += 256) {
            int id = p[e];
            unsigned int old = atomicAdd(&h32[id >> 2], 1u << (8 * (id & 3)));
            lrank[e] = (uchar8)((old >> (8 * (id & 3))) & 0xffu);
        }
    }
    __syncthreads();
    unsigned int* o32 = (unsigned int*)(partials + ((size_t)row * HNB + b) * HBINS);
    for (int i = t; i < HBINS / 4; i += 256) o32[i] = h32[i];
}

// row 0: sum partials -> rsqrt table.
// row 1: in-place exclusive scan of partials over chunks, total in_cnt, and
//        per-256-node block sums for the scan.
__global__ __launch_bounds__(256) void k_hist_reduce(uchar8* __restrict__ partials,
                                                     float* __restrict__ rsqrt_out,
                                                     int* __restrict__ in_cnt,
                                                     int* __restrict__ block_sums) {
    __shared__ int sm[256];
    int row = blockIdx.y;
    int i = blockIdx.x * 256 + threadIdx.x;
    if (row == 0) {
        const uchar8* p = partials + i;
        int s = 0;
#pragma unroll 4
        for (int b = 0; b < HNB; ++b) s += p[(size_t)b * HBINS];
        if (i < NNODES) rsqrt_out[i] = rsqrtf((float)s);
    } else {
        uchar8* p = partials + (size_t)HNB * HBINS + i;
        int run = 0;
        for (int b = 0; b < HNB; ++b) {
            int c = p[(size_t)b * HBINS];
            p[(size_t)b * HBINS] = (uchar8)run;
            run += c;
        }
        if (i < NNODES) in_cnt[i] = run;
        sm[threadIdx.x] = (i < NNODES) ? run : 0;
        __syncthreads();
        for (int off = 128; off > 0; off >>= 1) {
            if (threadIdx.x < off) sm[threadIdx.x] += sm[threadIdx.x + off];
            __syncthreads();
        }
        if (threadIdx.x == 0) block_sums[blockIdx.x] = sm[0];
    }
}

// ---------------- scan ----------------

__global__ void k_scan_blocks(const int* __restrict__ block_sums, int* __restrict__ block_base, int nb) {
    __shared__ int s[256];
    int t = threadIdx.x;
    int v = (t < nb) ? block_sums[t] : 0;
    s[t] = v;
    __syncthreads();
    for (int off = 1; off < 256; off <<= 1) {
        int u = (t >= off) ? s[t - off] : 0;
        __syncthreads();
        s[t] += u;
        __syncthreads();
    }
    block_base[t] = s[t] - v;  // exclusive
}

__global__ void k_scan_final(const int* __restrict__ in_cnt, const int* __restrict__ block_base,
                             int* __restrict__ offsets) {
    __shared__ int s[256];
    int b = blockIdx.x, t = threadIdx.x;
    int i = b * 256 + t;
    int v = (i < NNODES) ? in_cnt[i] : 0;
    s[t] = v;
    __syncthreads();
    for (int off = 1; off < 256; off <<= 1) {
        int u = (t >= off) ? s[t - off] : 0;
        __syncthreads();
        s[t] += u;
        __syncthreads();
    }
    int excl = s[t] - v + block_base[b];
    if (i < NNODES) offsets[i] = excl;
    if (i == NNODES - 1) offsets[NNODES] = excl + v;
}

// atomic-free counting-sort scatter, FUSED with the weight pack:
// blocks 0..1279 also transpose-pack [W|LW] -> bf16 BT (independent work; the
// scatter kernel completes before any GEMM reads wcat*, so no sync needed).
// pos = offsets[dst] + base[chunk(e)][dst] + lrank[e]  (bijective by construction)
__global__ __launch_bounds__(256) void k_scatter_pack(const int* __restrict__ ei,
                                                      const int* __restrict__ offsets,
                                                      const uchar8* __restrict__ partials,
                                                      const uchar8* __restrict__ lrank,
                                                      int* __restrict__ src_sorted,
                                                      const float* __restrict__ w1, const float* __restrict__ lw1,
                                                      const float* __restrict__ w2, const float* __restrict__ lw2,
                                                      const float* __restrict__ w3, const float* __restrict__ lw3,
                                                      bf16* __restrict__ o1, bf16* __restrict__ o2,
                                                      bf16* __restrict__ o3) {
    int gi = blockIdx.x * 256 + threadIdx.x;

    // weight pack: BT[n][k] = (n < C) ? W[k][n] : LW[k][n-C]
    if (gi < M1 + M2 + M3) {
        const float* W; const float* LW; bf16* O; int C; int j;
        if (gi < M1)           { W = w1; LW = lw1; O = o1; C = 256; j = gi; }
        else if (gi < M1 + M2) { W = w2; LW = lw2; O = o2; C = 256; j = gi - M1; }
        else                   { W = w3; LW = lw3; O = o3; C = 128; j = gi - M1 - M2; }
        int n = j >> 8, k = j & 255;   // K = 256 for all
        float v = (n < C) ? W[k * C + n] : LW[k * C + (n - C)];
        O[j] = __float2bfloat16(v);
    }

    // counting-sort scatter
    int e = gi;
    if (e < NEDGES) {
        int r = ei[e], c = ei[NEDGES + e];
        int b = e / HCHUNK;
        int pos = offsets[c] + (int)partials[(size_t)(HNB + b) * HBINS + c] + (int)lrank[e];
        src_sorted[pos] = r;
    }
}

// ---------------- fused aggregate + residual + bias + activation ----------------
// One 64-thread block per node (best-measured form, U=4, unchanged from R10).
template<int D, int ACT>
__global__ __launch_bounds__(64) void k_agg_fused(const bf16* __restrict__ xw,
                                                  const bf16* __restrict__ xlw,
                                                  const int* __restrict__ offsets,
                                                  const int* __restrict__ src_sorted,
                                                  const float* __restrict__ rsqrt_out,
                                                  const float* __restrict__ bias,
                                                  void* __restrict__ out) {
    const int L = D / 8;    // 32 (D=256) or 16 (D=128)
    const int G = 64 / L;   // 2 or 4
    const int U = 4;
    int lane = threadIdx.x;
    int v = blockIdx.x;
    int g = lane / L, sl = lane % L;

    int beg = offsets[v], end = offsets[v + 1];
    int deg = end - beg;
    int dcap = min(deg, 64);

    int id = 0; float wl = 0.f;
    if (lane < dcap) {
        id = src_sorted[beg + lane];
        wl = rsqrt_out[id];
    }

    float acc[U][8];
#pragma unroll
    for (int u = 0; u < U; ++u)
#pragma unroll
        for (int c = 0; c < 8; ++c) acc[u][c] = 0.f;

    const ushort* base = (const ushort*)xw + sl * 8;

    for (int e0 = 0; e0 < dcap; e0 += G * U) {
#pragma unroll
        for (int u = 0; u < U; ++u) {
            int e = e0 + u * G + g;
            int s = __shfl(id, e & 63, 64);
            float w = __shfl(wl, e & 63, 64);
            if (e >= dcap) w = 0.f;
            uint4 q = *(const uint4*)(base + (size_t)s * D);
            acc[u][0] += w * bflo(q.x); acc[u][1] += w * bfhi(q.x);
            acc[u][2] += w * bflo(q.y); acc[u][3] += w * bfhi(q.y);
            acc[u][4] += w * bflo(q.z); acc[u][5] += w * bfhi(q.z);
            acc[u][6] += w * bflo(q.w); acc[u][7] += w * bfhi(q.w);
        }
    }
    for (int j = beg + 64 + g; j < end; j += G) {
        int s = src_sorted[j];
        float w = rsqrt_out[s];
        uint4 q = *(const uint4*)(base + (size_t)s * D);
        acc[0][0] += w * bflo(q.x); acc[0][1] += w * bfhi(q.x);
        acc[0][2] += w * bflo(q.y); acc[0][3] += w * bfhi(q.y);
        acc[0][4] += w * bflo(q.z); acc[0][5] += w * bfhi(q.z);
        acc[0][6] += w * bflo(q.w); acc[0][7] += w * bfhi(q.w);
    }

#pragma unroll
    for (int c = 0; c < 8; ++c) acc[0][c] = (acc[0][c] + acc[1][c]) + (acc[2][c] + acc[3][c]);
#pragma unroll
    for (int d = 32; d >= L; d >>= 1) {
#pragma unroll
        for (int c = 0; c < 8; ++c) acc[0][c] += __shfl_down(acc[0][c], d, 64);
    }

    if (lane < L) {
        float sc = (deg > 0) ? rsqrtf((float)deg) : 0.f;
        const ushort* lwp = (const ushort*)xlw + (size_t)v * D + sl * 8;
        uint4 ql = *(const uint4*)lwp;
        const float* bp = bias + sl * 8;
        float4 b0 = *(const float4*)bp, b1 = *(const float4*)(bp + 4);
        float h[8];
        h[0] = acc[0][0] * sc + bflo(ql.x) + b0.x;
        h[1] = acc[0][1] * sc + bfhi(ql.x) + b0.y;
        h[2] = acc[0][2] * sc + bflo(ql.y) + b0.z;
        h[3] = acc[0][3] * sc + bfhi(ql.y) + b0.w;
        h[4] = acc[0][4] * sc + bflo(ql.z) + b1.x;
        h[5] = acc[0][5] * sc + bfhi(ql.z) + b1.y;
        h[6] = acc[0][6] * sc + bflo(ql.w) + b1.z;
        h[7] = acc[0][7] * sc + bfhi(ql.w) + b1.w;
        if (ACT == 1) {
            union { bf16 hh[8]; uint4 u; } o;
#pragma unroll
            for (int c = 0; c < 8; ++c) o.hh[c] = __float2bfloat16(fmaxf(h[c], 0.f));
            *(uint4*)((ushort*)out + (size_t)v * D + sl * 8) = o.u;
        } else {
            float r[8];
#pragma unroll
            for (int c = 0; c < 8; ++c) r[c] = 1.f / (1.f + expf(-h[c]));
            float* op = (float*)out + (size_t)v * D + sl * 8;
            *(float4*)op = (float4){r[0], r[1], r[2], r[3]};
            *(float4*)(op + 4) = (float4){r[4], r[5], r[6], r[7]};
        }
    }
}

// ---------------- m97-style MFMA GEMM: A[N,256] @ BT[C2,256]^T -> xw | xlw ----------------
// Best-measured form (R5/R10). Output columns [0,C2/2) -> compact gather array
// xw[N][C2/2]; columns [C2/2,C2) -> residual array xlw[N][C2/2]. Each 128-wide
// n-tile lies entirely in one half (tile-uniform routing).
template<int C2, bool A_BF16>
__global__ __launch_bounds__(256) void k_gemm2(const void* __restrict__ Aptr,
                                               const bf16* __restrict__ BT,
                                               bf16* __restrict__ XW,
                                               bf16* __restrict__ XLW) {
    constexpr int R = NNODES;
    constexpr int DH = C2 / 2;                 // 256 or 128
    constexpr int GX = (NNODES + 127) / 128;   // 391
    constexpr int GY = C2 / 128;               // 4 or 2
    constexpr int NWG = GX * GY;
    __shared__ bf16 As[128 * 32];
    __shared__ bf16 Bs[128 * 32];

    int o = blockIdx.x;
    constexpr int qq = NWG / 8, rr = NWG % 8;
    int xcd = o & 7, idx = o >> 3;
    int lt = (xcd < rr ? xcd * (qq + 1) : rr * (qq + 1) + (xcd - rr) * qq) + idx;
    int r0 = (lt / GY) * 128;
    int n0 = (lt % GY) * 128;

    int t = threadIdx.x;
    int wave = t >> 6, lane = t & 63;
    int wr = wave >> 1, wc = wave & 1;

    f4v acc[4][4];
#pragma unroll
    for (int mi = 0; mi < 4; ++mi)
#pragma unroll
        for (int ni = 0; ni < 4; ++ni) acc[mi][ni] = (f4v){0.f, 0.f, 0.f, 0.f};

    int sr = t >> 2;            // 0..63
    int sk = (t & 3) * 8;
    int fr = t >> 1, fs = (t & 1) * 16;

    for (int k0 = 0; k0 < 256; k0 += 32) {
        if (A_BF16) {
            const bf16* Ab = (const bf16*)Aptr;
            gload16(Ab + (size_t)min(r0 + sr, R - 1) * 256 + k0 + sk,
                    (char*)As + wave * 1024);
            gload16(Ab + (size_t)min(r0 + sr + 64, R - 1) * 256 + k0 + sk,
                    (char*)As + 4096 + wave * 1024);
        } else {
            const float* Af = (const float*)Aptr + (size_t)min(r0 + fr, R - 1) * 256 + k0 + fs;
            float4 f0 = ((const float4*)Af)[0];
            float4 f1 = ((const float4*)Af)[1];
            float4 f2 = ((const float4*)Af)[2];
            float4 f3 = ((const float4*)Af)[3];
            union { bf16 h[16]; uint4 u[2]; } cv;
            cv.h[0]  = __float2bfloat16(f0.x); cv.h[1]  = __float2bfloat16(f0.y);
            cv.h[2]  = __float2bfloat16(f0.z); cv.h[3]  = __float2bfloat16(f0.w);
            cv.h[4]  = __float2bfloat16(f1.x); cv.h[5]  = __float2bfloat16(f1.y);
            cv.h[6]  = __float2bfloat16(f1.z); cv.h[7]  = __float2bfloat16(f1.w);
            cv.h[8]  = __float2bfloat16(f2.x); cv.h[9]  = __float2bfloat16(f2.y);
            cv.h[10] = __float2bfloat16(f2.z); cv.h[11] = __float2bfloat16(f2.w);
            cv.h[12] = __float2bfloat16(f3.x); cv.h[13] = __float2bfloat16(f3.y);
            cv.h[14] = __float2bfloat16(f3.z); cv.h[15] = __float2bfloat16(f3.w);
            *(uint4*)&As[fr * 32 + fs]     = cv.u[0];
            *(uint4*)&As[fr * 32 + fs + 8] = cv.u[1];
        }
        gload16(BT + (size_t)(n0 + sr) * 256 + k0 + sk,
                (char*)Bs + wave * 1024);
        gload16(BT + (size_t)(n0 + sr + 64) * 256 + k0 + sk,
                (char*)Bs + 4096 + wave * 1024);
        __syncthreads();

        int lr = lane & 15, lk = (lane >> 4) * 8;
        s8v a[4], b[4];
#pragma unroll
        for (int mi = 0; mi < 4; ++mi)
            a[mi] = *(const s8v*)&As[(wr * 64 + mi * 16 + lr) * 32 + lk];
#pragma unroll
        for (int ni = 0; ni < 4; ++ni)
            b[ni] = *(const s8v*)&Bs[(wc * 64 + ni * 16 + lr) * 32 + lk];
#pragma unroll
        for (int mi = 0; mi < 4; ++mi)
#pragma unroll
            for (int ni = 0; ni < 4; ++ni)
                acc[mi][ni] = __builtin_amdgcn_mfma_f32_16x16x32_bf16(a[mi], b[ni], acc[mi][ni], 0, 0, 0);
        __syncthreads();
    }

    // route this block's 128-wide n-tile to xw or xlw (tile-uniform)
    bool isXW = (n0 < DH);
    bf16* OutH = isXW ? XW : XLW;
    int   c0   = isXW ? n0 : n0 - DH;

    int lr = lane & 15, lq = (lane >> 4) * 4;
#pragma unroll
    for (int mi = 0; mi < 4; ++mi) {
#pragma unroll
        for (int rj = 0; rj < 4; ++rj) {
            int grow = r0 + wr * 64 + mi * 16 + lq + rj;
            if (grow < R) {
#pragma unroll
                for (int ni = 0; ni < 4; ++ni) {
                    OutH[(size_t)grow * DH + c0 + wc * 64 + ni * 16 + lr] =
                        __float2bfloat16(acc[mi][ni][rj]);
                }
            }
        }
    }
}

// ---------------- launcher ----------------

extern "C" void kernel_launch(void* const* d_in, const int* in_sizes, int n_in,
                              void* d_out, int out_size, void* d_ws, size_t ws_size,
                              hipStream_t stream) {
    const float* x   = (const float*)d_in[0];
    const int*   ei  = (const int*)d_in[1];
    const float* w1  = (const float*)d_in[3];
    const float* lw1 = (const float*)d_in[4];
    const float* lb1 = (const float*)d_in[5];
    const float* w2  = (const float*)d_in[6];
    const float* lw2 = (const float*)d_in[7];
    const float* lb2 = (const float*)d_in[8];
    const float* w3  = (const float*)d_in[9];
    const float* lw3 = (const float*)d_in[10];
    const float* lb3 = (const float*)d_in[11];
    float* out = (float*)d_out;

    char* ws = (char*)d_ws;
    size_t off = 0;
    auto alloc = [&](size_t bytes) -> void* {
        void* p = ws + off;
        off += (bytes + 255) & ~(size_t)255;
        return p;
    };
    int*    in_cnt     = (int*)alloc((size_t)HBINS * 4);
    float*  rsqrt_out  = (float*)alloc((size_t)HBINS * 4);
    int*    offsets    = (int*)alloc((size_t)(NNODES + 1) * 4);
    int*    block_sums = (int*)alloc((size_t)256 * 4);
    int*    block_base = (int*)alloc((size_t)256 * 4);
    uchar8* partials   = (uchar8*)alloc((size_t)2 * HNB * HBINS);
    uchar8* lrank      = (uchar8*)alloc((size_t)NEDGES);
    int*    src_sorted = (int*)alloc((size_t)NEDGES * 4);
    bf16*   wcat1      = (bf16*)alloc((size_t)256 * 512 * 2);
    bf16*   wcat2      = (bf16*)alloc((size_t)256 * 512 * 2);
    bf16*   wcat3      = (bf16*)alloc((size_t)256 * 256 * 2);
    bf16*   xw         = (bf16*)alloc((size_t)NNODES * 256 * 2);   // compact gather array
    bf16*   xlw        = (bf16*)alloc((size_t)NNODES * 256 * 2);   // residual rows
    bf16*   h1         = (bf16*)alloc((size_t)NNODES * 256 * 2);
    bf16*   h2         = (bf16*)alloc((size_t)NNODES * 256 * 2);

    // graph preprocessing: u8 LDS histograms (+rank record) -> in-place chunk
    // scan -> node scan -> atomic-free scatter (fused with weight pack)
    k_hist<<<dim3(HNB, 2), 256, 0, stream>>>(ei, partials, lrank);
    k_hist_reduce<<<dim3(SCAN_NB, 2), 256, 0, stream>>>(partials, rsqrt_out, in_cnt, block_sums);
    k_scan_blocks<<<1, 256, 0, stream>>>(block_sums, block_base, SCAN_NB);
    k_scan_final<<<SCAN_NB, 256, 0, stream>>>(in_cnt, block_base, offsets);
    int eblocks = (NEDGES + 255) / 256;
    k_scatter_pack<<<eblocks, 256, 0, stream>>>(ei, offsets, partials, lrank, src_sorted,
                                                w1, lw1, w2, lw2, w3, lw3, wcat1, wcat2, wcat3);

    // layer 1 (A fp32)
    k_gemm2<512, false><<<391 * 4, 256, 0, stream>>>(x, wcat1, xw, xlw);
    k_agg_fused<256, 1><<<NNODES, 64, 0, stream>>>(xw, xlw, offsets, src_sorted, rsqrt_out, lb1, h1);
    // layer 2 (A bf16)
    k_gemm2<512, true><<<391 * 4, 256, 0, stream>>>(h1, wcat2, xw, xlw);
    k_agg_fused<256, 1><<<NNODES, 64, 0, stream>>>(xw, xlw, offsets, src_sorted, rsqrt_out, lb2, h2);
    // layer 3 (A bf16)
    k_gemm2<256, true><<<391 * 2, 256, 0, stream>>>(h2, wcat3, xw, xlw);
    k_agg_fused<128, 2><<<NNODES, 64, 0, stream>>>(xw, xlw, offsets, src_sorted, rsqrt_out, lb3, out);
}